// Round 5
// baseline (407.952 us; speedup 1.0000x reference)
//
#include <hip/hip_runtime.h>
#include <stdint.h>

#define H_N 16
#define S_N 2048
#define D_N 64
#define QB  64
#define KT  64

typedef __attribute__((ext_vector_type(8))) __bf16 bf16x8;
typedef __attribute__((ext_vector_type(4))) float f32x4;

__device__ __forceinline__ unsigned short f2bf(float f) {
  uint32_t u = __float_as_uint(f);
  u += 0x7FFFu + ((u >> 16) & 1u);   // round-to-nearest-even
  return (unsigned short)(u >> 16);
}

// JAX threefry2x32, key=(0,42): full 20-round block, both output lanes.
__device__ __forceinline__ uint2 tf2x32(uint32_t c0, uint32_t c1) {
  const uint32_t K0 = 0u, K1 = 42u, K2 = 0x1BD11BDAu ^ 42u;
  uint32_t x0 = c0 + K0, x1 = c1 + K1;
#define TFR(r) x0 += x1; x1 = __builtin_rotateleft32(x1, r); x1 ^= x0;
  TFR(13) TFR(15) TFR(26) TFR(6)
  x0 += K1; x1 += K2 + 1u;
  TFR(17) TFR(29) TFR(16) TFR(24)
  x0 += K2; x1 += K0 + 2u;
  TFR(13) TFR(15) TFR(26) TFR(6)
  x0 += K0; x1 += K1 + 3u;
  TFR(17) TFR(29) TFR(16) TFR(24)
  x0 += K1; x1 += K2 + 4u;
  TFR(13) TFR(15) TFR(26) TFR(6)
  x0 += K2; x1 += K0 + 5u;
#undef TFR
  return make_uint2(x0, x1);
}

// Modern JAX partitionable random_bits(32) at flat index j (j < 2^32):
//   counts1, counts2 = iota_2x32_shape(shape) -> (0, j)
//   bits1, bits2 = threefry2x32(key, (0, j))
//   bits = bits1 ^ bits2                      <- XOR combine (prng.py)
// keep <=> float32 uniform from bits < 0.9f <=> (bits>>9) < 0x733333.
__device__ __forceinline__ bool keep_bit(uint32_t j) {
  uint2 o = tf2x32(0u, j);
  return (((o.x ^ o.y) >> 9) < 0x733333u);
}

// Stage a contiguous [64 rows][64 cols] fp32 tile -> bf16 LDS tile, XOR-swizzled.
// swizzled ushort idx for element (row,col): row*64 + (((col>>3)^(row&7))<<3) + (col&7)
__device__ __forceinline__ void stageTile(const float* __restrict__ g,
                                          unsigned short* __restrict__ lds, int tid) {
  const int row = tid >> 2;
  const int c4  = tid & 3;
  const float4* s = (const float4*)(g + (tid << 4));
  float4 a = s[0], b = s[1], c = s[2], d = s[3];
  uint4 q0, q1;
  q0.x = (uint32_t)f2bf(a.x) | ((uint32_t)f2bf(a.y) << 16);
  q0.y = (uint32_t)f2bf(a.z) | ((uint32_t)f2bf(a.w) << 16);
  q0.z = (uint32_t)f2bf(b.x) | ((uint32_t)f2bf(b.y) << 16);
  q0.w = (uint32_t)f2bf(b.z) | ((uint32_t)f2bf(b.w) << 16);
  q1.x = (uint32_t)f2bf(c.x) | ((uint32_t)f2bf(c.y) << 16);
  q1.y = (uint32_t)f2bf(c.z) | ((uint32_t)f2bf(c.w) << 16);
  q1.z = (uint32_t)f2bf(d.x) | ((uint32_t)f2bf(d.y) << 16);
  q1.w = (uint32_t)f2bf(d.z) | ((uint32_t)f2bf(d.w) << 16);
  const int rs = row & 7;
  *(uint4*)&lds[row * 64 + (((c4 * 2)     ^ rs) << 3)] = q0;
  *(uint4*)&lds[row * 64 + (((c4 * 2 + 1) ^ rs) << 3)] = q1;
}

// Stage V tile [64 keys][64 d] fp32 -> TRANSPOSED bf16 LDS tile [d][key], swizzled.
__device__ __forceinline__ void stageTileT(const float* __restrict__ g,
                                           unsigned short* __restrict__ lds, int tid) {
  const int key = tid >> 2;
  const int c4  = tid & 3;
  const float4* s = (const float4*)(g + (tid << 4));
  float4 v0 = s[0], v1 = s[1], v2 = s[2], v3 = s[3];
  const int kc = key >> 3, ke = key & 7;
#define WRT(e, val) { const int dd = c4 * 16 + (e); \
    lds[dd * 64 + (((kc ^ (dd & 7)) << 3) | ke)] = f2bf(val); }
  WRT(0,  v0.x) WRT(1,  v0.y) WRT(2,  v0.z) WRT(3,  v0.w)
  WRT(4,  v1.x) WRT(5,  v1.y) WRT(6,  v1.z) WRT(7,  v1.w)
  WRT(8,  v2.x) WRT(9,  v2.y) WRT(10, v2.z) WRT(11, v2.w)
  WRT(12, v3.x) WRT(13, v3.y) WRT(14, v3.z) WRT(15, v3.w)
#undef WRT
}

__global__ __launch_bounds__(256, 2)
void attn_fused(const float* __restrict__ Q, const float* __restrict__ K,
                const float* __restrict__ V, const int* __restrict__ mask,
                float* __restrict__ outO, float* __restrict__ outP) {
  __shared__ uint4 smemRaw[4096];               // 64 KB
  unsigned short* const sbase = (unsigned short*)smemRaw;
  unsigned short* const sQ[2] = {sbase,          sbase + 4096};
  unsigned short* const sK[2] = {sbase + 8192,   sbase + 12288};
  unsigned short* const sV[2] = {sbase + 16384,  sbase + 20480};
  unsigned short* const sP[2] = {sbase + 24576,  sbase + 28672};

  const int tid = threadIdx.x;
  const int l   = tid & 63;
  const int w   = tid >> 6;
  const int h   = blockIdx.x & (H_N - 1);
  const int qt  = blockIdx.x >> 4;
  const int qBase = qt * QB;

  const int lrow = l & 15;   // col-lane / A-row lane
  const int lq4  = l >> 4;   // 0..3

  const size_t base0 = (size_t)h * (S_N * D_N);
  const size_t base1 = (size_t)(H_N + h) * (S_N * D_N);

  // ---- stage Q (both b), load A-frags, keep in regs for both passes
  stageTile(Q + base0 + (size_t)qBase * D_N, sQ[0], tid);
  stageTile(Q + base1 + (size_t)qBase * D_N, sQ[1], tid);
  __syncthreads();

  bf16x8 qf[2][2];
  {
    const int qrow = w * 16 + lrow;
#pragma unroll
    for (int b = 0; b < 2; ++b)
#pragma unroll
      for (int ks = 0; ks < 2; ++ks) {
        const int cc = ks * 4 + lq4;
        qf[b][ks] = *(const bf16x8*)&sQ[b][qrow * 64 + ((cc ^ (qrow & 7)) << 3)];
      }
  }

  // ---- pass 1: row sums of mask * exp(score - 20)
  float invl[2][4];
  {
    float lsum[2][4] = {{0.f,0.f,0.f,0.f},{0.f,0.f,0.f,0.f}};
    for (int kt = 0; kt < S_N / KT; ++kt) {
      __syncthreads();
      stageTile(K + base0 + (size_t)(kt * KT) * D_N, sK[0], tid);
      stageTile(K + base1 + (size_t)(kt * KT) * D_N, sK[1], tid);
      __syncthreads();
#pragma unroll
      for (int b = 0; b < 2; ++b) {
#pragma unroll
        for (int n = 0; n < 4; ++n) {
          const int krow = n * 16 + lrow;
          f32x4 acc = {0.f, 0.f, 0.f, 0.f};
#pragma unroll
          for (int ks = 0; ks < 2; ++ks) {
            const int cc = ks * 4 + lq4;
            bf16x8 kf = *(const bf16x8*)&sK[b][krow * 64 + ((cc ^ (krow & 7)) << 3)];
            acc = __builtin_amdgcn_mfma_f32_16x16x32_bf16(qf[b][ks], kf, acc, 0, 0, 0);
          }
          const float mf = (float)mask[b * S_N + kt * KT + krow];
#pragma unroll
          for (int r = 0; r < 4; ++r)
            lsum[b][r] += mf * __expf(acc[r] * 0.125f - 20.0f);
        }
      }
    }
#pragma unroll
    for (int b = 0; b < 2; ++b)
#pragma unroll
      for (int r = 0; r < 4; ++r) {
        float v = lsum[b][r];
        v += __shfl_xor(v, 1);
        v += __shfl_xor(v, 2);
        v += __shfl_xor(v, 4);
        v += __shfl_xor(v, 8);
        invl[b][r] = (v > 0.f) ? (1.0f / v) : 0.f;
      }
  }

  // ---- pass 2: recompute scores, dropout, write p, accumulate PV
  f32x4 oacc[2][4];
#pragma unroll
  for (int b = 0; b < 2; ++b)
#pragma unroll
    for (int n = 0; n < 4; ++n)
      oacc[b][n] = (f32x4){0.f, 0.f, 0.f, 0.f};

  const uint32_t qg = (uint32_t)(qBase + w * 16 + lq4 * 4);  // first of this lane's 4 C-rows

  for (int kt = 0; kt < S_N / KT; ++kt) {
    __syncthreads();
    stageTile (K + base0 + (size_t)(kt * KT) * D_N, sK[0], tid);
    stageTile (K + base1 + (size_t)(kt * KT) * D_N, sK[1], tid);
    stageTileT(V + base0 + (size_t)(kt * KT) * D_N, sV[0], tid);
    stageTileT(V + base1 + (size_t)(kt * KT) * D_N, sV[1], tid);
    __syncthreads();

#pragma unroll
    for (int b = 0; b < 2; ++b) {
#pragma unroll
      for (int n = 0; n < 4; ++n) {
        const int krow = n * 16 + lrow;
        f32x4 acc = {0.f, 0.f, 0.f, 0.f};
#pragma unroll
        for (int ks = 0; ks < 2; ++ks) {
          const int cc = ks * 4 + lq4;
          bf16x8 kf = *(const bf16x8*)&sK[b][krow * 64 + ((cc ^ (krow & 7)) << 3)];
          acc = __builtin_amdgcn_mfma_f32_16x16x32_bf16(qf[b][ks], kf, acc, 0, 0, 0);
        }
        const int kg = kt * KT + krow;
        const float mf = (float)mask[b * S_N + kg];
        const size_t pBase = (size_t)(b * H_N + h) * (size_t)(S_N * S_N);
        const uint32_t j0 = (uint32_t)(b * H_N + h) * 4194304u + qg * 2048u + (uint32_t)kg;
#pragma unroll
        for (int r = 0; r < 4; ++r) {
          const float p = mf * __expf(acc[r] * 0.125f - 20.0f) * invl[b][r];
          const bool keep = keep_bit(j0 + (uint32_t)r * 2048u);
          const float pd = keep ? p * (1.0f / 0.9f) : 0.0f;
          __builtin_nontemporal_store(pd, &outP[pBase + (size_t)(qg + r) * S_N + (size_t)kg]);
          const int prow = w * 16 + lq4 * 4 + r;
          sP[b][prow * 64 + ((((krow >> 3) ^ (prow & 7)) << 3) | (krow & 7))] = f2bf(pd);
        }
      }
      // PV: out[q][d] += P[q][key] * V[key][d]
#pragma unroll
      for (int ks = 0; ks < 2; ++ks) {
        const int cc = ks * 4 + lq4;
        const int prow = w * 16 + lrow;
        bf16x8 af = *(const bf16x8*)&sP[b][prow * 64 + ((cc ^ (prow & 7)) << 3)];
#pragma unroll
        for (int n = 0; n < 4; ++n) {
          const int vrow = n * 16 + lrow;
          bf16x8 vf = *(const bf16x8*)&sV[b][vrow * 64 + ((cc ^ (vrow & 7)) << 3)];
          oacc[b][n] = __builtin_amdgcn_mfma_f32_16x16x32_bf16(af, vf, oacc[b][n], 0, 0, 0);
        }
      }
    }
  }

  // ---- store out
#pragma unroll
  for (int b = 0; b < 2; ++b)
#pragma unroll
    for (int n = 0; n < 4; ++n)
#pragma unroll
      for (int r = 0; r < 4; ++r) {
        const size_t off = ((size_t)(b * H_N + h) * S_N + (size_t)(qg + r)) * D_N + n * 16 + lrow;
        __builtin_nontemporal_store(oacc[b][n][r], &outO[off]);
      }
}

extern "C" void kernel_launch(void* const* d_in, const int* in_sizes, int n_in,
                              void* d_out, int out_size, void* d_ws, size_t ws_size,
                              hipStream_t stream) {
  const float* Q   = (const float*)d_in[0];
  const float* K   = (const float*)d_in[1];
  const float* V   = (const float*)d_in[2];
  const int* mask  = (const int*)d_in[3];
  float* outO = (float*)d_out;
  float* outP = outO + (size_t)2 * H_N * S_N * D_N;   // out first, then p_attn
  hipLaunchKernelGGL(attn_fused, dim3(512), dim3(256), 0, stream,
                     Q, K, V, mask, outO, outP);
}

// Round 6
// 369.005 us; speedup vs baseline: 1.1055x; 1.1055x over previous
//
#include <hip/hip_runtime.h>
#include <stdint.h>

#define H_N 16
#define S_N 2048
#define D_N 64
#define QB  64
#define KT  64

typedef __attribute__((ext_vector_type(8))) __bf16 bf16x8;
typedef __attribute__((ext_vector_type(4))) float f32x4;

__device__ __forceinline__ unsigned short f2bf(float f) {
  uint32_t u = __float_as_uint(f);
  u += 0x7FFFu + ((u >> 16) & 1u);   // round-to-nearest-even
  return (unsigned short)(u >> 16);
}

// JAX threefry2x32, key=(0,42): full 20-round block, both output lanes.
__device__ __forceinline__ uint2 tf2x32(uint32_t c0, uint32_t c1) {
  const uint32_t K0 = 0u, K1 = 42u, K2 = 0x1BD11BDAu ^ 42u;
  uint32_t x0 = c0 + K0, x1 = c1 + K1;
#define TFR(r) x0 += x1; x1 = __builtin_rotateleft32(x1, r); x1 ^= x0;
  TFR(13) TFR(15) TFR(26) TFR(6)
  x0 += K1; x1 += K2 + 1u;
  TFR(17) TFR(29) TFR(16) TFR(24)
  x0 += K2; x1 += K0 + 2u;
  TFR(13) TFR(15) TFR(26) TFR(6)
  x0 += K0; x1 += K1 + 3u;
  TFR(17) TFR(29) TFR(16) TFR(24)
  x0 += K1; x1 += K2 + 4u;
  TFR(13) TFR(15) TFR(26) TFR(6)
  x0 += K2; x1 += K0 + 5u;
#undef TFR
  return make_uint2(x0, x1);
}

// Modern JAX partitionable random_bits(32) at flat index j:
// bits = x0 ^ x1 of threefry(key, (0, j)); keep <=> (bits>>9) < 0x733333.
__device__ __forceinline__ bool keep_bit(uint32_t j) {
  uint2 o = tf2x32(0u, j);
  return (((o.x ^ o.y) >> 9) < 0x733333u);
}

// Stage a contiguous [64 rows][64 cols] fp32 tile -> bf16 LDS tile, XOR-swizzled.
// swizzled ushort idx for element (row,col): row*64 + (((col>>3)^(row&7))<<3) + (col&7)
__device__ __forceinline__ void stageTile(const float* __restrict__ g,
                                          unsigned short* __restrict__ lds, int tid) {
  const int row = tid >> 2;
  const int c4  = tid & 3;
  const float4* s = (const float4*)(g + (tid << 4));
  float4 a = s[0], b = s[1], c = s[2], d = s[3];
  uint4 q0, q1;
  q0.x = (uint32_t)f2bf(a.x) | ((uint32_t)f2bf(a.y) << 16);
  q0.y = (uint32_t)f2bf(a.z) | ((uint32_t)f2bf(a.w) << 16);
  q0.z = (uint32_t)f2bf(b.x) | ((uint32_t)f2bf(b.y) << 16);
  q0.w = (uint32_t)f2bf(b.z) | ((uint32_t)f2bf(b.w) << 16);
  q1.x = (uint32_t)f2bf(c.x) | ((uint32_t)f2bf(c.y) << 16);
  q1.y = (uint32_t)f2bf(c.z) | ((uint32_t)f2bf(c.w) << 16);
  q1.z = (uint32_t)f2bf(d.x) | ((uint32_t)f2bf(d.y) << 16);
  q1.w = (uint32_t)f2bf(d.z) | ((uint32_t)f2bf(d.w) << 16);
  const int rs = row & 7;
  *(uint4*)&lds[row * 64 + (((c4 * 2)     ^ rs) << 3)] = q0;
  *(uint4*)&lds[row * 64 + (((c4 * 2 + 1) ^ rs) << 3)] = q1;
}

// Stage V tile [64 keys][64 d] fp32 -> TRANSPOSED bf16 LDS tile [d][key], swizzled.
__device__ __forceinline__ void stageTileT(const float* __restrict__ g,
                                           unsigned short* __restrict__ lds, int tid) {
  const int key = tid >> 2;
  const int c4  = tid & 3;
  const float4* s = (const float4*)(g + (tid << 4));
  float4 v0 = s[0], v1 = s[1], v2 = s[2], v3 = s[3];
  const int kc = key >> 3, ke = key & 7;
#define WRT(e, val) { const int dd = c4 * 16 + (e); \
    lds[dd * 64 + (((kc ^ (dd & 7)) << 3) | ke)] = f2bf(val); }
  WRT(0,  v0.x) WRT(1,  v0.y) WRT(2,  v0.z) WRT(3,  v0.w)
  WRT(4,  v1.x) WRT(5,  v1.y) WRT(6,  v1.z) WRT(7,  v1.w)
  WRT(8,  v2.x) WRT(9,  v2.y) WRT(10, v2.z) WRT(11, v2.w)
  WRT(12, v3.x) WRT(13, v3.y) WRT(14, v3.z) WRT(15, v3.w)
#undef WRT
}

__global__ __launch_bounds__(256, 4)
void attn_fused(const float* __restrict__ Q, const float* __restrict__ K,
                const float* __restrict__ V, const int* __restrict__ mask,
                float* __restrict__ outO, float* __restrict__ outP) {
  __shared__ uint4 smemRaw[2048];               // 32 KB -> 4 blocks/CU
  unsigned short* const sbase = (unsigned short*)smemRaw;
  unsigned short* const sQ = sbase;
  unsigned short* const sK = sbase + 4096;
  unsigned short* const sV = sbase + 8192;
  unsigned short* const sP = sbase + 12288;

  const int tid = threadIdx.x;
  const int l   = tid & 63;
  const int w   = tid >> 6;
  const int bid = blockIdx.x;
  const int b   = bid & 1;
  const int h   = (bid >> 1) & (H_N - 1);
  const int qt  = bid >> 5;
  const int qBase = qt * QB;

  const int lrow = l & 15;   // col-lane / A-row lane
  const int lq4  = l >> 4;   // 0..3

  const size_t base = ((size_t)b * H_N + h) * (size_t)(S_N * D_N);
  const int* const maskRow = mask + b * S_N;

  // ---- stage Q, load A-frags, keep in regs for both passes
  stageTile(Q + base + (size_t)qBase * D_N, sQ, tid);
  __syncthreads();

  bf16x8 qf[2];
  {
    const int qrow = w * 16 + lrow;
#pragma unroll
    for (int ks = 0; ks < 2; ++ks) {
      const int cc = ks * 4 + lq4;
      qf[ks] = *(const bf16x8*)&sQ[qrow * 64 + ((cc ^ (qrow & 7)) << 3)];
    }
  }

  // ---- pass 1: row sums of mask * exp(score - 20)
  float minv[4];   // (1/rowsum) * (1/0.9), folded
  {
    float lsum[4] = {0.f, 0.f, 0.f, 0.f};
    for (int kt = 0; kt < S_N / KT; ++kt) {
      __syncthreads();
      stageTile(K + base + (size_t)(kt * KT) * D_N, sK, tid);
      __syncthreads();
#pragma unroll
      for (int n = 0; n < 4; ++n) {
        const int krow = n * 16 + lrow;
        f32x4 acc = {0.f, 0.f, 0.f, 0.f};
#pragma unroll
        for (int ks = 0; ks < 2; ++ks) {
          const int cc = ks * 4 + lq4;
          bf16x8 kf = *(const bf16x8*)&sK[krow * 64 + ((cc ^ (krow & 7)) << 3)];
          acc = __builtin_amdgcn_mfma_f32_16x16x32_bf16(qf[ks], kf, acc, 0, 0, 0);
        }
        const float mf = (float)maskRow[kt * KT + krow];
#pragma unroll
        for (int r = 0; r < 4; ++r)
          lsum[r] += mf * __expf(acc[r] * 0.125f - 20.0f);
      }
    }
#pragma unroll
    for (int r = 0; r < 4; ++r) {
      float v = lsum[r];
      v += __shfl_xor(v, 1);
      v += __shfl_xor(v, 2);
      v += __shfl_xor(v, 4);
      v += __shfl_xor(v, 8);
      minv[r] = (v > 0.f) ? ((1.0f / 0.9f) / v) : 0.f;
    }
  }

  // ---- pass 2: recompute scores, dropout, write p, accumulate PV
  f32x4 oacc[4];
#pragma unroll
  for (int n = 0; n < 4; ++n)
    oacc[n] = (f32x4){0.f, 0.f, 0.f, 0.f};

  const uint32_t qg = (uint32_t)(qBase + w * 16 + lq4 * 4);  // first of this lane's 4 C-rows
  const size_t pBase = ((size_t)b * H_N + h) * (size_t)(S_N * S_N);
  const uint32_t jBase = (uint32_t)(b * H_N + h) * 4194304u + qg * 2048u;

  for (int kt = 0; kt < S_N / KT; ++kt) {
    __syncthreads();
    stageTile (K + base + (size_t)(kt * KT) * D_N, sK, tid);
    stageTileT(V + base + (size_t)(kt * KT) * D_N, sV, tid);
    __syncthreads();

#pragma unroll
    for (int n = 0; n < 4; ++n) {
      const int krow = n * 16 + lrow;
      f32x4 acc = {0.f, 0.f, 0.f, 0.f};
#pragma unroll
      for (int ks = 0; ks < 2; ++ks) {
        const int cc = ks * 4 + lq4;
        bf16x8 kf = *(const bf16x8*)&sK[krow * 64 + ((cc ^ (krow & 7)) << 3)];
        acc = __builtin_amdgcn_mfma_f32_16x16x32_bf16(qf[ks], kf, acc, 0, 0, 0);
      }
      const int kg = kt * KT + krow;
      const float mf = (float)maskRow[kg];
      const uint32_t j0 = jBase + (uint32_t)kg;
#pragma unroll
      for (int r = 0; r < 4; ++r) {
        const float pe = mf * __expf(acc[r] * 0.125f - 20.0f) * minv[r];
        const bool keep = keep_bit(j0 + (uint32_t)r * 2048u);
        const float pd = keep ? pe : 0.0f;
        __builtin_nontemporal_store(pd, &outP[pBase + (size_t)(qg + r) * S_N + (size_t)kg]);
        const int prow = w * 16 + lq4 * 4 + r;
        sP[prow * 64 + ((((krow >> 3) ^ (prow & 7)) << 3) | (krow & 7))] = f2bf(pd);
      }
    }
    // PV: out[q][d] += P[q][key] * V[key][d]  (sP rows are warp-private)
#pragma unroll
    for (int ks = 0; ks < 2; ++ks) {
      const int cc = ks * 4 + lq4;
      const int prow = w * 16 + lrow;
      bf16x8 af = *(const bf16x8*)&sP[prow * 64 + ((cc ^ (prow & 7)) << 3)];
#pragma unroll
      for (int n = 0; n < 4; ++n) {
        const int vrow = n * 16 + lrow;
        bf16x8 vf = *(const bf16x8*)&sV[vrow * 64 + ((cc ^ (vrow & 7)) << 3)];
        oacc[n] = __builtin_amdgcn_mfma_f32_16x16x32_bf16(af, vf, oacc[n], 0, 0, 0);
      }
    }
  }

  // ---- store out
#pragma unroll
  for (int n = 0; n < 4; ++n)
#pragma unroll
    for (int r = 0; r < 4; ++r) {
      const size_t off = (((size_t)b * H_N + h) * S_N + (size_t)(qg + r)) * D_N + n * 16 + lrow;
      __builtin_nontemporal_store(oacc[n][r], &outO[off]);
    }
}

extern "C" void kernel_launch(void* const* d_in, const int* in_sizes, int n_in,
                              void* d_out, int out_size, void* d_ws, size_t ws_size,
                              hipStream_t stream) {
  const float* Q   = (const float*)d_in[0];
  const float* K   = (const float*)d_in[1];
  const float* V   = (const float*)d_in[2];
  const int* mask  = (const int*)d_in[3];
  float* outO = (float*)d_out;
  float* outP = outO + (size_t)2 * H_N * S_N * D_N;   // out first, then p_attn
  hipLaunchKernelGGL(attn_fused, dim3(1024), dim3(256), 0, stream,
                     Q, K, V, mask, outO, outP);
}